// Round 4
// baseline (21.764 us; speedup 1.0000x reference)
//
#include <hip/hip_runtime.h>
#include <stdint.h>

#define THREADS 64
#define BOARDS_PER_BLOCK 128   // 2 boards per thread, 1 wave per block

// Column-range mask in 7-wide layout: bit = 7*r + c, r=0 top .. 5 bottom.
static constexpr uint64_t colmask(int lo, int hi) {
    uint64_t m = 0;
    for (int r = 0; r < 6; ++r)
        for (int c = lo; c <= hi; ++c)
            m |= 1ull << (7 * r + c);
    return m;
}

// Cells where placing a piece of `P`'s color completes 4-in-a-row.
// 7-wide layout; column-wrap handled by per-term column masks.
static __device__ __forceinline__ uint64_t win_cells(uint64_t P) {
    uint64_t w = 0;
    #pragma unroll
    for (int d = 0; d < 4; ++d) {
        const int s  = (d == 0) ? 1 : (d == 1) ? 7 : (d == 2) ? 8 : 6;
        const int dc = (d == 0) ? 1 : (d == 1) ? 0 : (d == 2) ? 1 : -1;
        const uint64_t M0 = (dc == 0) ? ~0ull : (dc > 0 ? colmask(0, 3) : colmask(3, 6));
        const uint64_t M1 = (dc == 0) ? ~0ull : (dc > 0 ? colmask(1, 4) : colmask(2, 5));
        const uint64_t M2 = (dc == 0) ? ~0ull : (dc > 0 ? colmask(2, 5) : colmask(1, 4));
        const uint64_t M3 = (dc == 0) ? ~0ull : (dc > 0 ? colmask(3, 6) : colmask(0, 3));
        uint64_t r1 = P >> s, r2 = P >> (2 * s), r3 = P >> (3 * s);
        uint64_t l1 = P << s, l2 = P << (2 * s), l3 = P << (3 * s);
        uint64_t u = r1 & r2, v = l1 & l2;
        w |= (u & r3 & M0) | (u & l1 & M1) | (v & r1 & M2) | (v & l3 & M3);
    }
    return w;
}

// OR all 6 rows (period 7) into the low 7 bits.
static __device__ __forceinline__ uint32_t colfold(uint64_t v) {
    v |= v >> 21;
    v |= v >> 7;
    v |= v >> 7;
    return (uint32_t)v & 0x7Fu;
}

extern "C" __global__ void __launch_bounds__(THREADS)
c4_kernel(const float* __restrict__ x, float* __restrict__ out)
{
    __shared__ uint32_t s_pk[BOARDS_PER_BLOCK * 42 / 4];  // 1344 dwords = 5376 B
    __shared__ float    s_out[BOARDS_PER_BLOCK * 7];      // 3584 B

    const int tid = threadIdx.x;
    const size_t board0 = (size_t)blockIdx.x * BOARDS_PER_BLOCK;

    // ---- coalesced global -> LDS, compressing each cell to its top byte ----
    // bit5 (0x20): occupied (0x3f / 0xbf), bit7 (0x80): cell is -1 (0xbf)
    const float4* src = reinterpret_cast<const float4*>(x) + (size_t)blockIdx.x * 1344u;
    #pragma unroll
    for (int k = 0; k < 21; ++k) {
        int n = k * THREADS + tid;              // lane-consecutive 16B loads
        float4 v = src[n];
        uint32_t a = __float_as_uint(v.x), b = __float_as_uint(v.y),
                 c = __float_as_uint(v.z), d = __float_as_uint(v.w);
        uint32_t lo = __builtin_amdgcn_perm(b, a, 0x00000703u) & 0x0000FFFFu;
        uint32_t hi = __builtin_amdgcn_perm(d, c, 0x07030000u) & 0xFFFF0000u;
        s_pk[n] = lo | hi;                      // dword n = cells 4n..4n+3
    }
    __syncthreads();                            // 1-wave group: near-free

    // ---- per-thread: 21 aligned dwords = 2 boards' 84 cell-bytes ----
    const uint32_t* pk = s_pk + tid * 21;
    uint64_t occ[2] = {0, 0}, MM[2] = {0, 0};
    #pragma unroll
    for (int j = 0; j < 21; ++j) {
        uint32_t e = pk[j];
        uint32_t nO = ((e & 0x20202020u) * 0x00204081u) >> 26;  // occupied
        uint32_t nM = ((e & 0x80808080u) * 0x00204081u) >> 28;  // minus
        if (j < 10) {
            occ[0] |= (uint64_t)nO << (4 * j);
            MM[0]  |= (uint64_t)nM << (4 * j);
        } else if (j == 10) {                   // cells 40,41 | 42,43 straddle
            occ[0] |= (uint64_t)(nO & 3u) << 40;
            MM[0]  |= (uint64_t)(nM & 3u) << 40;
            occ[1] |= (uint64_t)(nO >> 2);
            MM[1]  |= (uint64_t)(nM >> 2);
        } else {
            occ[1] |= (uint64_t)nO << (4 * j - 42);
            MM[1]  |= (uint64_t)nM << (4 * j - 42);
        }
    }

    #pragma unroll
    for (int b = 0; b < 2; ++b) {
        uint64_t o = occ[b], m = MM[b], p = o & ~m;
        const uint64_t ROW5 = 0x7Full << 35;    // bottom row
        uint64_t land = ~o & ((o >> 7) | ROW5); // landing cell per column

        uint32_t cp = colfold(land & win_cells(p));  // +1 winning columns
        uint32_t cm = colfold(land & win_cells(m));  // -1 winning columns
        uint32_t sel = cp ? cp : cm;                 // +1 takes precedence
        bool any = (sel != 0u);
        int col  = __ffs(sel) - 1;                   // lowest winning column

        float* so = s_out + (2 * tid + b) * 7;
        #pragma unroll
        for (int c = 0; c < 7; ++c)
            so[c] = (any && c != col) ? -27.631021f : 0.0f;
    }
    __syncthreads();

    // ---- coalesced LDS -> global: 896 floats per block ----
    float* dst = out + board0 * 7u;
    #pragma unroll
    for (int k = 0; k < 14; ++k) {
        int n = k * THREADS + tid;
        dst[n] = s_out[n];
    }
}

extern "C" void kernel_launch(void* const* d_in, const int* in_sizes, int n_in,
                              void* d_out, int out_size, void* d_ws, size_t ws_size,
                              hipStream_t stream)
{
    const float* x = (const float*)d_in[0];
    float* out = (float*)d_out;
    const int N = in_sizes[0] / 42;                 // 524288 boards
    const int grid = N / BOARDS_PER_BLOCK;          // 4096 blocks = 16 per CU
    hipLaunchKernelGGL(c4_kernel, dim3(grid), dim3(THREADS), 0, stream, x, out);
}

// Round 6
// 19.337 us; speedup vs baseline: 1.1255x; 1.1255x over previous
//
#include <hip/hip_runtime.h>
#include <stdint.h>

#define THREADS 64
#define BOARDS_PER_BLOCK 128   // 2 boards per thread, 1 wave per block

typedef float f32x4 __attribute__((ext_vector_type(4)));  // native vec for nt-load

// Column-range mask in 7-wide layout: bit = 7*r + c, r=0 top .. 5 bottom.
static constexpr uint64_t colmask(int lo, int hi) {
    uint64_t m = 0;
    for (int r = 0; r < 6; ++r)
        for (int c = lo; c <= hi; ++c)
            m |= 1ull << (7 * r + c);
    return m;
}

// Cells where placing a piece of `P`'s color completes 4-in-a-row.
// 7-wide layout; column-wrap handled by per-term column masks.
static __device__ __forceinline__ uint64_t win_cells(uint64_t P) {
    uint64_t w = 0;
    #pragma unroll
    for (int d = 0; d < 4; ++d) {
        const int s  = (d == 0) ? 1 : (d == 1) ? 7 : (d == 2) ? 8 : 6;
        const int dc = (d == 0) ? 1 : (d == 1) ? 0 : (d == 2) ? 1 : -1;
        const uint64_t M0 = (dc == 0) ? ~0ull : (dc > 0 ? colmask(0, 3) : colmask(3, 6));
        const uint64_t M1 = (dc == 0) ? ~0ull : (dc > 0 ? colmask(1, 4) : colmask(2, 5));
        const uint64_t M2 = (dc == 0) ? ~0ull : (dc > 0 ? colmask(2, 5) : colmask(1, 4));
        const uint64_t M3 = (dc == 0) ? ~0ull : (dc > 0 ? colmask(3, 6) : colmask(0, 3));
        uint64_t r1 = P >> s, r2 = P >> (2 * s), r3 = P >> (3 * s);
        uint64_t l1 = P << s, l2 = P << (2 * s), l3 = P << (3 * s);
        uint64_t u = r1 & r2, v = l1 & l2;
        w |= (u & r3 & M0) | (u & l1 & M1) | (v & r1 & M2) | (v & l3 & M3);
    }
    return w;
}

// OR all 6 rows (period 7) into the low 7 bits.
static __device__ __forceinline__ uint32_t colfold(uint64_t v) {
    v |= v >> 21;
    v |= v >> 7;
    v |= v >> 7;
    return (uint32_t)v & 0x7Fu;
}

extern "C" __global__ void __launch_bounds__(THREADS)
c4_kernel(const float* __restrict__ x, float* __restrict__ out)
{
    __shared__ uint32_t s_pk[BOARDS_PER_BLOCK * 42 / 4];  // 1344 dwords = 5376 B
    __shared__ float    s_out[BOARDS_PER_BLOCK * 7];      // 3584 B

    const int tid = threadIdx.x;
    const size_t board0 = (size_t)blockIdx.x * BOARDS_PER_BLOCK;

    // ---- coalesced NON-TEMPORAL global -> LDS, cell -> top byte ----
    // bit5 (0x20): occupied (0x3f / 0xbf), bit7 (0x80): cell is -1 (0xbf)
    const f32x4* src = reinterpret_cast<const f32x4*>(x) + (size_t)blockIdx.x * 1344u;
    #pragma unroll
    for (int k = 0; k < 21; ++k) {
        int n = k * THREADS + tid;              // lane-consecutive 16B loads
        f32x4 v = __builtin_nontemporal_load(&src[n]);   // nt: don't pollute L3
        uint32_t a = __float_as_uint(v.x), b = __float_as_uint(v.y),
                 c = __float_as_uint(v.z), d = __float_as_uint(v.w);
        uint32_t lo = __builtin_amdgcn_perm(b, a, 0x00000703u) & 0x0000FFFFu;
        uint32_t hi = __builtin_amdgcn_perm(d, c, 0x07030000u) & 0xFFFF0000u;
        s_pk[n] = lo | hi;                      // dword n = cells 4n..4n+3
    }
    __syncthreads();                            // 1-wave group: near-free

    // ---- per-thread: 21 aligned dwords = 2 boards' 84 cell-bytes ----
    const uint32_t* pk = s_pk + tid * 21;
    uint64_t occ[2] = {0, 0}, MM[2] = {0, 0};
    #pragma unroll
    for (int j = 0; j < 21; ++j) {
        uint32_t e = pk[j];
        uint32_t nO = ((e & 0x20202020u) * 0x00204081u) >> 26;  // occupied
        uint32_t nM = ((e & 0x80808080u) * 0x00204081u) >> 28;  // minus
        if (j < 10) {
            occ[0] |= (uint64_t)nO << (4 * j);
            MM[0]  |= (uint64_t)nM << (4 * j);
        } else if (j == 10) {                   // cells 40,41 | 42,43 straddle
            occ[0] |= (uint64_t)(nO & 3u) << 40;
            MM[0]  |= (uint64_t)(nM & 3u) << 40;
            occ[1] |= (uint64_t)(nO >> 2);
            MM[1]  |= (uint64_t)(nM >> 2);
        } else {
            occ[1] |= (uint64_t)nO << (4 * j - 42);
            MM[1]  |= (uint64_t)nM << (4 * j - 42);
        }
    }

    #pragma unroll
    for (int b = 0; b < 2; ++b) {
        uint64_t o = occ[b], m = MM[b], p = o & ~m;
        const uint64_t ROW5 = 0x7Full << 35;    // bottom row
        uint64_t land = ~o & ((o >> 7) | ROW5); // landing cell per column

        uint32_t cp = colfold(land & win_cells(p));  // +1 winning columns
        uint32_t cm = colfold(land & win_cells(m));  // -1 winning columns
        uint32_t sel = cp ? cp : cm;                 // +1 takes precedence
        bool any = (sel != 0u);
        int col  = __ffs(sel) - 1;                   // lowest winning column

        float* so = s_out + (2 * tid + b) * 7;
        #pragma unroll
        for (int c = 0; c < 7; ++c)
            so[c] = (any && c != col) ? -27.631021f : 0.0f;
    }
    __syncthreads();

    // ---- coalesced NON-TEMPORAL LDS -> global: 896 floats per block ----
    float* dst = out + board0 * 7u;
    #pragma unroll
    for (int k = 0; k < 14; ++k) {
        int n = k * THREADS + tid;
        __builtin_nontemporal_store(s_out[n], &dst[n]);
    }
}

extern "C" void kernel_launch(void* const* d_in, const int* in_sizes, int n_in,
                              void* d_out, int out_size, void* d_ws, size_t ws_size,
                              hipStream_t stream)
{
    const float* x = (const float*)d_in[0];
    float* out = (float*)d_out;
    const int N = in_sizes[0] / 42;                 // 524288 boards
    const int grid = N / BOARDS_PER_BLOCK;          // 4096 blocks = 16 per CU
    hipLaunchKernelGGL(c4_kernel, dim3(grid), dim3(THREADS), 0, stream, x, out);
}